// Round 2
// baseline (1599.537 us; speedup 1.0000x reference)
//
#include <hip/hip_runtime.h>

// Problem constants (fixed-shape: B=8192, IN=1024, N=4096, K=409)
#define BATCH 8192
#define INF   1024
#define NF    4096
#define BN_EPS 1e-5

// ---------------------------------------------------------------------------
// Kernel 1: zero the f64 stats accumulators (2*4096 doubles)
// ---------------------------------------------------------------------------
__global__ void zero_ws(double* __restrict__ p) {
    p[blockIdx.x * 256 + threadIdx.x] = 0.0;
}

// ---------------------------------------------------------------------------
// Kernel 2: masked f64 GEMM: Y[r][n] = sum_i x[r][i]*W[n][i]*mask[n][i] + b[n]
// Tile 128x64 (MxN), BK=16, 256 threads, f64 accumulate, stored as f32.
// f64 LDS staging (converted once) to keep cvt out of the inner loop.
// ---------------------------------------------------------------------------
__global__ __launch_bounds__(256) void gemm_mask_f64(
    const float* __restrict__ X, const float* __restrict__ W,
    const int* __restrict__ Mk, const float* __restrict__ bias,
    float* __restrict__ Y)
{
    __shared__ double As[16][132];   // [k][row], 128 rows + pad
    __shared__ double Bs[16][68];    // [k][col], 64 cols + pad

    const int t = threadIdx.x;
    const int row0 = blockIdx.y * 128;
    const int col0 = blockIdx.x * 64;

    // A loads: 128 rows x 16 k floats = 512 float4 -> 2 per thread
    const int alr = t >> 1;            // 0..127
    const int alk = (t & 1) * 8;       // 0 or 8
    // B loads: 64 rows x 16 k -> 1 float4 + 1 int4 per thread
    const int blr = t >> 2;            // 0..63
    const int blk = (t & 3) * 4;       // 0,4,8,12

    const float* Xp = X + (size_t)(row0 + alr) * INF + alk;
    const float* Wp = W + (size_t)(col0 + blr) * INF + blk;
    const int*   Mp = Mk + (size_t)(col0 + blr) * INF + blk;

    const int tx = t & 15;             // col group: tx*4
    const int ty = t >> 4;             // row group: ty*8

    double acc[8][4];
#pragma unroll
    for (int i = 0; i < 8; ++i)
#pragma unroll
        for (int j = 0; j < 4; ++j) acc[i][j] = 0.0;

    for (int k0 = 0; k0 < INF; k0 += 16) {
        const float4 a0 = *(const float4*)(Xp + k0);
        const float4 a1 = *(const float4*)(Xp + k0 + 4);
        float4 b0 = *(const float4*)(Wp + k0);
        const int4 m0 = *(const int4*)(Mp + k0);
        b0.x *= (float)m0.x; b0.y *= (float)m0.y;
        b0.z *= (float)m0.z; b0.w *= (float)m0.w;

        __syncthreads();   // protect previous iteration's LDS reads
        As[alk + 0][alr] = (double)a0.x; As[alk + 1][alr] = (double)a0.y;
        As[alk + 2][alr] = (double)a0.z; As[alk + 3][alr] = (double)a0.w;
        As[alk + 4][alr] = (double)a1.x; As[alk + 5][alr] = (double)a1.y;
        As[alk + 6][alr] = (double)a1.z; As[alk + 7][alr] = (double)a1.w;
        Bs[blk + 0][blr] = (double)b0.x; Bs[blk + 1][blr] = (double)b0.y;
        Bs[blk + 2][blr] = (double)b0.z; Bs[blk + 3][blr] = (double)b0.w;
        __syncthreads();

#pragma unroll
        for (int kk = 0; kk < 16; ++kk) {
            const double* ap = &As[kk][ty * 8];
            const double* bp = &Bs[kk][tx * 4];
            double ad[8], bd[4];
#pragma unroll
            for (int i = 0; i < 8; ++i) ad[i] = ap[i];
#pragma unroll
            for (int j = 0; j < 4; ++j) bd[j] = bp[j];
#pragma unroll
            for (int i = 0; i < 8; ++i)
#pragma unroll
                for (int j = 0; j < 4; ++j)
                    acc[i][j] = fma(ad[i], bd[j], acc[i][j]);
        }
    }

    // epilogue: add bias (f64), store f32
#pragma unroll
    for (int i = 0; i < 8; ++i) {
        const int rr = row0 + ty * 8 + i;
        float4 o;
        o.x = (float)(acc[i][0] + (double)bias[col0 + tx * 4 + 0]);
        o.y = (float)(acc[i][1] + (double)bias[col0 + tx * 4 + 1]);
        o.z = (float)(acc[i][2] + (double)bias[col0 + tx * 4 + 2]);
        o.w = (float)(acc[i][3] + (double)bias[col0 + tx * 4 + 3]);
        *(float4*)&Y[(size_t)rr * NF + col0 + tx * 4] = o;
    }
}

// ---------------------------------------------------------------------------
// Kernel 3: per-column partial sums (f64) over 256-row chunks
// ---------------------------------------------------------------------------
__global__ __launch_bounds__(256) void stats_partial(
    const float* __restrict__ Y, double* __restrict__ dsum, double* __restrict__ dsqs)
{
    const int col = blockIdx.x * 256 + threadIdx.x;
    const int r0  = blockIdx.y * 256;
    double s = 0.0, ss = 0.0;
    for (int i = 0; i < 256; ++i) {
        const float v = Y[(size_t)(r0 + i) * NF + col];
        s  += (double)v;
        ss += (double)v * (double)v;
    }
    atomicAdd(&dsum[col], s);
    atomicAdd(&dsqs[col], ss);
}

// ---------------------------------------------------------------------------
// Kernel 4: finalize mean / rstd / boost (f64 + f32 copies)
// ---------------------------------------------------------------------------
__global__ __launch_bounds__(256) void stats_final(
    const double* __restrict__ dsum, const double* __restrict__ dsqs,
    const float* __restrict__ duty, const int* __restrict__ kp,
    double* __restrict__ mean64, double* __restrict__ rstd64, double* __restrict__ boost64,
    float* __restrict__ mean32, float* __restrict__ rstd32, float* __restrict__ boost32)
{
    const int c = blockIdx.x * 256 + threadIdx.x;
    const double m   = dsum[c] / (double)BATCH;
    const double var = dsqs[c] / (double)BATCH - m * m;
    const double rs  = 1.0 / sqrt(var + (double)BN_EPS);
    const double td  = (double)(*kp) / (double)NF;
    const double bf  = exp(td - (double)duty[c]);
    mean64[c] = m;  rstd64[c] = rs;  boost64[c] = bf;
    mean32[c] = (float)m; rstd32[c] = (float)rs; boost32[c] = (float)bf;
}

// ---------------------------------------------------------------------------
// Kernel 5: per-row BN-apply + boosted top-k (radix select, f32) with f64
// band refinement near the cutoff + scatter (in place). One block per row.
// ---------------------------------------------------------------------------
#define BAND 1e-4f
#define MAXCAND 64

__global__ __launch_bounds__(256) void topk_kernel(
    const float* __restrict__ mean32, const float* __restrict__ rstd32,
    const float* __restrict__ boost32,
    const double* __restrict__ mean64, const double* __restrict__ rstd64,
    const double* __restrict__ boost64,
    const int* __restrict__ kp,
    const float* __restrict__ X, const float* __restrict__ W,
    const int* __restrict__ Mk, const float* __restrict__ bias,
    float* __restrict__ Y)
{
    __shared__ float    yv[NF];
    __shared__ unsigned keys[NF];
    __shared__ unsigned hist[256];
    __shared__ unsigned scan[256];
    __shared__ unsigned s_bin, s_below;
    __shared__ double   red[256];
    __shared__ int      s_ncand, s_H;
    __shared__ int      cand_idx[MAXCAND];
    __shared__ double   cand_val[MAXCAND];
    __shared__ unsigned char cand_pick[MAXCAND];

    const int r = blockIdx.x;
    const int t = threadIdx.x;
    const int K = *kp;

    // load row, apply BN, compute orderable keys of boosted values
    for (int j = 0; j < 16; ++j) {
        const int n = j * 256 + t;
        const float v   = Y[(size_t)r * NF + n];
        const float ybn = (v - mean32[n]) * rstd32[n];
        yv[n] = ybn;
        const float bst = ybn * boost32[n];
        unsigned u = __float_as_uint(bst);
        u ^= (u & 0x80000000u) ? 0xFFFFFFFFu : 0x80000000u;  // monotonic map
        keys[n] = u;
    }
    __syncthreads();

    // 4-pass radix select: find T = K-th largest key
    unsigned curval = 0u, curmask = 0u;
    int remaining = K;
    for (int pass = 3; pass >= 0; --pass) {
        const int sh = pass * 8;
        hist[t] = 0u;
        __syncthreads();
        for (int j = 0; j < 16; ++j) {
            const unsigned u = keys[j * 256 + t];
            if ((u & curmask) == curval)
                atomicAdd(&hist[(u >> sh) & 255u], 1u);
        }
        __syncthreads();
        scan[t] = hist[t];
        __syncthreads();
        for (int off = 1; off < 256; off <<= 1) {
            const unsigned add = (t + off < 256) ? scan[t + off] : 0u;
            __syncthreads();
            scan[t] += add;
            __syncthreads();
        }
        if (scan[t] >= (unsigned)remaining &&
            (t == 255 || scan[t + 1] < (unsigned)remaining)) {
            s_bin = (unsigned)t;
            s_below = (t == 255) ? 0u : scan[t + 1];
        }
        __syncthreads();
        curval |= (s_bin << sh);
        curmask |= (255u << sh);
        remaining -= (int)s_below;
        __syncthreads();
    }

    const unsigned T = curval;

    // cutoff value as float (invert the monotonic map)
    const unsigned vT = (T & 0x80000000u) ? (T ^ 0x80000000u) : ~T;
    const float cut32 = __uint_as_float(vT);
    const float cutHi = cut32 + BAND;
    const float cutLo = cut32 - BAND;

    // classify: count definite-selects (H) and collect band candidates
    if (t == 0) { s_ncand = 0; s_H = 0; }
    __syncthreads();
    int locH = 0;
    for (int j = 0; j < 16; ++j) {
        const int n = j * 256 + t;
        const float b = yv[n] * boost32[n];
        if (b > cutHi) {
            locH++;
        } else if (b >= cutLo) {
            const int slot = atomicAdd(&s_ncand, 1);
            if (slot < MAXCAND) cand_idx[slot] = n;
        }
    }
    atomicAdd(&s_H, locH);
    __syncthreads();
    const int H = s_H;
    const bool overflow = (s_ncand > MAXCAND);
    const int ncand = overflow ? MAXCAND : s_ncand;
    int need = K - H;
    if (need < 0) need = 0;

    if (!overflow) {
        // recompute each candidate's boosted value in f64
        for (int c = 0; c < ncand; ++c) {
            const int n = cand_idx[c];
            const float* xr = X + (size_t)r * INF;
            const float* wn = W + (size_t)n * INF;
            const int*   mn = Mk + (size_t)n * INF;
            double s = 0.0;
            for (int i = t; i < INF; i += 256)
                s += (double)xr[i] * (double)(wn[i] * (float)mn[i]);
            red[t] = s;
            __syncthreads();
            for (int off = 128; off > 0; off >>= 1) {
                if (t < off) red[t] += red[t + off];
                __syncthreads();
            }
            if (t == 0) {
                const double y64 = red[0] + (double)bias[n];
                cand_val[c] = (y64 - mean64[n]) * rstd64[n] * boost64[n];
                cand_pick[c] = 0;
            }
            __syncthreads();
        }
        // serial exact selection of `need` best (value desc, index asc)
        if (t == 0) {
            for (int p = 0; p < need; ++p) {
                int best = -1;
                for (int c = 0; c < ncand; ++c) {
                    if (cand_pick[c]) continue;
                    if (best < 0 || cand_val[c] > cand_val[best] ||
                        (cand_val[c] == cand_val[best] && cand_idx[c] < cand_idx[best]))
                        best = c;
                }
                if (best < 0) break;
                cand_pick[best] = 1;
            }
        }
        __syncthreads();
        // build selection flags in keys[]
        for (int j = 0; j < 16; ++j) {
            const int n = j * 256 + t;
            const float b = yv[n] * boost32[n];
            keys[n] = (b > cutHi) ? 1u : 0u;
        }
        __syncthreads();
        if (t < ncand && cand_pick[t]) keys[cand_idx[t]] = 1u;
        __syncthreads();
    } else {
        // fallback: pure f32 stable selection (lowest-index ties at T)
        const int fneed = remaining;
        unsigned cnt = 0u;
        for (int j = 0; j < 16; ++j) cnt += (keys[t * 16 + j] == T) ? 1u : 0u;
        scan[t] = cnt;
        __syncthreads();
        for (int off = 1; off < 256; off <<= 1) {
            const unsigned add = (t >= off) ? scan[t - off] : 0u;
            __syncthreads();
            scan[t] += add;
            __syncthreads();
        }
        unsigned rank = scan[t] - cnt;
        for (int j = 0; j < 16; ++j) {
            const int n = t * 16 + j;
            const unsigned u = keys[n];
            bool sel;
            if (u == T) { sel = ((int)rank < fneed); rank++; }
            else        { sel = (u > T); }
            keys[n] = sel ? 1u : 0u;
        }
        __syncthreads();
    }

    // coalesced in-place write
    for (int j = 0; j < 16; ++j) {
        const int n = j * 256 + t;
        Y[(size_t)r * NF + n] = keys[n] ? yv[n] : 0.0f;
    }
}

// ---------------------------------------------------------------------------
extern "C" void kernel_launch(void* const* d_in, const int* in_sizes, int n_in,
                              void* d_out, int out_size, void* d_ws, size_t ws_size,
                              hipStream_t stream)
{
    const float* x     = (const float*)d_in[0];
    const float* W     = (const float*)d_in[1];
    const float* b     = (const float*)d_in[2];
    const int*   wmask = (const int*)d_in[3];
    const float* duty  = (const float*)d_in[4];
    const int*   kp    = (const int*)d_in[5];
    float* out = (float*)d_out;

    double* dsum   = (double*)d_ws;          // [4096]
    double* dsqs   = dsum + NF;              // [4096]
    double* mean64 = dsqs + NF;              // [4096]
    double* rstd64 = mean64 + NF;            // [4096]
    double* boost64 = rstd64 + NF;           // [4096]
    float*  mean32 = (float*)(boost64 + NF); // [4096]
    float*  rstd32 = mean32 + NF;            // [4096]
    float*  boost32 = rstd32 + NF;           // [4096]

    hipLaunchKernelGGL(zero_ws, dim3(2 * NF / 256), dim3(256), 0, stream, dsum);
    hipLaunchKernelGGL(gemm_mask_f64, dim3(NF / 64, BATCH / 128), dim3(256), 0, stream,
                       x, W, wmask, b, out);
    hipLaunchKernelGGL(stats_partial, dim3(NF / 256, BATCH / 256), dim3(256), 0, stream,
                       out, dsum, dsqs);
    hipLaunchKernelGGL(stats_final, dim3(NF / 256), dim3(256), 0, stream,
                       dsum, dsqs, duty, kp,
                       mean64, rstd64, boost64, mean32, rstd32, boost32);
    hipLaunchKernelGGL(topk_kernel, dim3(BATCH), dim3(256), 0, stream,
                       mean32, rstd32, boost32, mean64, rstd64, boost64, kp,
                       x, W, wmask, b, out);
}